// Round 10
// baseline (335.343 us; speedup 1.0000x reference)
//
#include <hip/hip_runtime.h>
#include <math.h>

// Problem constants
#define BB 32
#define PP 2048
#define DD 768
#define TT 3
#define OO 128
#define HH 192
#define CC 32              // chunks of P per batch for the streaming phase
#define ROWS (PP / CC)     // 64 rows per chunk
#define VC 1024            // fixed virtual chunks for main phase (determinism)
#define ASTR 16            // release slot stride (64B lines)
#define SCALE 0.03608439182435161f  // 1/sqrt(768)
#define GELU_C 0.70710678118654752f

struct Params {
    const float* x; const int* mask; const float* tt;
    const float* Wq; const float* bq; const float* Wk;
    const float* Wv; const float* bv; const float* Wo; const float* bo;
    const float* h1w; const float* h1b; const float* h2w; const float* h2b;
    float* out;
    unsigned* arr;     // 1024 packed arrival dwords
    unsigned* rel;     // 256 padded release lines (<=4 pollers each)
    float* q; float* kq; float* xap; float* lp;
};

// L3-coherent (L2-bypassing) accessors for inter-phase intermediates.
// RELAXED agent-scope => sc-flagged load/store, NO buffer_wbl2 / buffer_inv.
__device__ inline float ld(const float* p) {
    return __hip_atomic_load(p, __ATOMIC_RELAXED, __HIP_MEMORY_SCOPE_AGENT);
}
__device__ inline void st(float* p, float v) {
    __hip_atomic_store(p, v, __ATOMIC_RELAXED, __HIP_MEMORY_SCOPE_AGENT);
}

// ---------------------------------------------------------------------------
// Grid barrier v3 (round-8 verified) — zero cache-maintenance ops.
// ---------------------------------------------------------------------------
__device__ inline void gbar(unsigned* arr, unsigned* rel, int phase) {
    __syncthreads();   // drains vmcnt/lgkmcnt for every wave of this block
    const int grid = gridDim.x;
    const unsigned ph = (unsigned)phase;
    if (blockIdx.x == 0) {
        if (threadIdx.x == 0)
            __hip_atomic_store(&arr[0], ph, __ATOMIC_RELAXED,
                               __HIP_MEMORY_SCOPE_AGENT);
        for (unsigned it = 0; it < (1u << 22); ++it) {
            int ok = 1;
            for (int s = threadIdx.x; s < grid; s += 256)
                ok &= (__hip_atomic_load(&arr[s], __ATOMIC_RELAXED,
                                         __HIP_MEMORY_SCOPE_AGENT) >= ph);
            if (__syncthreads_and(ok)) break;
            __builtin_amdgcn_s_sleep(1);
        }
        asm volatile("" ::: "memory");
        __hip_atomic_store(&rel[threadIdx.x * ASTR], ph, __ATOMIC_RELAXED,
                           __HIP_MEMORY_SCOPE_AGENT);
        __syncthreads();
    } else {
        if (threadIdx.x == 0) {
            __hip_atomic_store(&arr[blockIdx.x], ph, __ATOMIC_RELAXED,
                               __HIP_MEMORY_SCOPE_AGENT);
            unsigned* myrel = &rel[(blockIdx.x & 255) * ASTR];
            for (unsigned it = 0; it < (1u << 22); ++it) {
                if (__hip_atomic_load(myrel, __ATOMIC_RELAXED,
                                      __HIP_MEMORY_SCOPE_AGENT) >= ph)
                    break;
                __builtin_amdgcn_s_sleep(1);
            }
            asm volatile("" ::: "memory");
        }
        __syncthreads();
    }
}

// ---------------------------------------------------------------------------
// One fused kernel, 4 phases / 3 grid barriers.
//   P1 q (144 vblocks) | bar | P2 kq (576) | bar | P3 main (1024) | bar |
//   PC per-(t,b) chained tail (96) — no internal grid barriers.
// ---------------------------------------------------------------------------
__global__ __launch_bounds__(256, 4) void fused(Params p) {
    __shared__ union {
        struct { float red[4][TT * DD]; float redl[4][TT]; } m;    // 36912 B
        float qred[16][16];                                        // P1
        struct { float xa[DD], yv[DD], y2[DD], hv[HH]; } c;        // PC ~10KB
    } u;

    const int bid = blockIdx.x;
    const int tid = threadIdx.x;
    const int grid = gridDim.x;

    // ---- Phase 1: q[t,e] = tt[t,:]·Wq[t,:,e] + bq  (144 virtual blocks) ---
    for (int vb = bid; vb < TT * 48; vb += grid) {
        int t = vb / 48, ec = vb % 48;
        int le = tid & 15, kg = tid >> 4;
        int e = ec * 16 + le;
        const float* w  = p.Wq + (size_t)t * DD * DD + e;
        const float* tr = p.tt + t * DD;
        float a = 0.f;
#pragma unroll 4
        for (int d = kg * 48; d < kg * 48 + 48; ++d)
            a += tr[d] * w[(size_t)d * DD];
        u.qred[kg][le] = a;
        __syncthreads();
        if (kg == 0) {
            float s = p.bq[t * DD + e];
#pragma unroll
            for (int i = 0; i < 16; ++i) s += u.qred[i][le];
            st(&p.q[t * DD + e], s);
        }
        __syncthreads();
    }
    gbar(p.arr, p.rel, 1);

    // ---- Phase 2: kq[t,d] = SCALE * Wk[t,d,:]·q[t]  (576 virtual) ---------
    for (int vb = bid; vb < TT * 192; vb += grid) {
        int t = vb / 192;
        int d = (vb % 192) * 4 + (tid >> 6);
        int L = tid & 63;
        const float4* wr = (const float4*)(p.Wk + (size_t)(t * DD + d) * DD);
        const float* qb = p.q + t * DD;
        float s = 0.f;
#pragma unroll
        for (int g = 0; g < 3; ++g) {
            float4 a = wr[g * 64 + L];
            int qi = g * 256 + 4 * L;
            s += a.x * ld(&qb[qi]) + a.y * ld(&qb[qi + 1])
               + a.z * ld(&qb[qi + 2]) + a.w * ld(&qb[qi + 3]);
        }
#pragma unroll
        for (int off = 32; off; off >>= 1) s += __shfl_xor(s, off);
        if (L == 0) st(&p.kq[t * DD + d], s * SCALE);
    }
    gbar(p.arr, p.rel, 2);

    // ---- Phase 3: MAIN stream over x (1024 fixed virtual chunks) ----------
    {
        const int w = tid >> 6, L = tid & 63;
        float4 kqr[TT][3];
#pragma unroll
        for (int t = 0; t < TT; ++t)
#pragma unroll
            for (int g = 0; g < 3; ++g) {
                int base = t * DD + g * 256 + 4 * L;
                kqr[t][g].x = ld(&p.kq[base]);
                kqr[t][g].y = ld(&p.kq[base + 1]);
                kqr[t][g].z = ld(&p.kq[base + 2]);
                kqr[t][g].w = ld(&p.kq[base + 3]);
            }

        for (int vc = bid; vc < VC; vc += grid) {
            int b = vc >> 5, c = vc & 31;

            float4 acc[TT][3] = {};
            float l[TT] = {0.f, 0.f, 0.f};
            const float* xb = p.x + (size_t)b * PP * DD;
            const int* mb = p.mask + b * PP;
            int p0 = c * ROWS + w * 16;

            // prefetch 16 masks -> bitmask
            const int4* m4 = (const int4*)&mb[p0];
            int4 ma = m4[0], mbv = m4[1], mc = m4[2], md = m4[3];
            unsigned bits = 0;
            bits |= (ma.x  != 0) << 0;  bits |= (ma.y  != 0) << 1;
            bits |= (ma.z  != 0) << 2;  bits |= (ma.w  != 0) << 3;
            bits |= (mbv.x != 0) << 4;  bits |= (mbv.y != 0) << 5;
            bits |= (mbv.z != 0) << 6;  bits |= (mbv.w != 0) << 7;
            bits |= (mc.x  != 0) << 8;  bits |= (mc.y  != 0) << 9;
            bits |= (mc.z  != 0) << 10; bits |= (mc.w  != 0) << 11;
            bits |= (md.x  != 0) << 12; bits |= (md.y  != 0) << 13;
            bits |= (md.z  != 0) << 14; bits |= (md.w  != 0) << 15;

#pragma unroll 4
            for (int r = 0; r < 16; ++r) {
                if (bits & (1u << r)) continue;    // masked rows contribute 0
                const float4* xr = (const float4*)(xb + (size_t)(p0 + r) * DD);
                float4 xv[3];
#pragma unroll
                for (int g = 0; g < 3; ++g) xv[g] = xr[g * 64 + L];
                float s[TT];
#pragma unroll
                for (int t = 0; t < TT; ++t) {
                    float a = 0.f;
#pragma unroll
                    for (int g = 0; g < 3; ++g)
                        a += xv[g].x * kqr[t][g].x + xv[g].y * kqr[t][g].y
                           + xv[g].z * kqr[t][g].z + xv[g].w * kqr[t][g].w;
                    s[t] = a;
                }
#pragma unroll
                for (int off = 32; off; off >>= 1) {
                    s[0] += __shfl_xor(s[0], off);
                    s[1] += __shfl_xor(s[1], off);
                    s[2] += __shfl_xor(s[2], off);
                }
#pragma unroll
                for (int t = 0; t < TT; ++t) {
                    float e = __expf(s[t]);        // scores tiny; no max needed
                    l[t] += e;
#pragma unroll
                    for (int g = 0; g < 3; ++g) {
                        acc[t][g].x += e * xv[g].x;
                        acc[t][g].y += e * xv[g].y;
                        acc[t][g].z += e * xv[g].z;
                        acc[t][g].w += e * xv[g].w;
                    }
                }
            }

            __syncthreads();
#pragma unroll
            for (int t = 0; t < TT; ++t)
#pragma unroll
                for (int g = 0; g < 3; ++g)
                    *(float4*)&u.m.red[w][t * DD + g * 256 + 4 * L] = acc[t][g];
            if (L == 0) {
#pragma unroll
                for (int t = 0; t < TT; ++t) u.m.redl[w][t] = l[t];
            }
            __syncthreads();

            float* outp = p.xap + (size_t)vc * (TT * DD);
#pragma unroll
            for (int k = 0; k < 9; ++k) {
                int i = tid + k * 256;
                st(&outp[i], u.m.red[0][i] + u.m.red[1][i]
                           + u.m.red[2][i] + u.m.red[3][i]);
            }
            if (tid < TT)
                st(&p.lp[vc * TT + tid], u.m.redl[0][tid] + u.m.redl[1][tid]
                                       + u.m.redl[2][tid] + u.m.redl[3][tid]);
        }
    }
    gbar(p.arr, p.rel, 3);

    // ---- Phase C: per-(t,b) chained tail (96 virtual blocks, no gbars) ----
    for (int vb = bid; vb < TT * BB; vb += grid) {
        int t = vb >> 5, b = vb & 31;

        // 1) softmax denominator (all threads redundantly; broadcast loads)
        float lsum = 0.f;
#pragma unroll
        for (int c = 0; c < CC; ++c) lsum += ld(&p.lp[(b * CC + c) * TT + t]);
        float inv = 1.0f / lsum;

        // 2) xa[d] = (sum_c xap)/lsum  -> LDS
#pragma unroll
        for (int k = 0; k < 3; ++k) {
            int d = tid + k * 256;
            float s = 0.f;
#pragma unroll
            for (int c = 0; c < CC; ++c)
                s += ld(&p.xap[(size_t)(b * CC + c) * (TT * DD) + t * DD + d]);
            u.c.xa[d] = s * inv;
        }
        __syncthreads();

        // 3) y = xa @ Wv + bv  -> LDS   (W cols lane-coalesced, xa broadcast)
#pragma unroll
        for (int k = 0; k < 3; ++k) {
            int e = tid + k * 256;
            float s = p.bv[t * DD + e];
            const float* wc = p.Wv + (size_t)t * DD * DD + e;
#pragma unroll 8
            for (int d = 0; d < DD; ++d)
                s += u.c.xa[d] * wc[(size_t)d * DD];
            u.c.yv[e] = s;
        }
        __syncthreads();

        // 4) y2 = y @ Wo + bo + tt  -> LDS
#pragma unroll
        for (int k = 0; k < 3; ++k) {
            int f = tid + k * 256;
            float s = p.bo[t * DD + f] + p.tt[t * DD + f];
            const float* wc = p.Wo + (size_t)t * DD * DD + f;
#pragma unroll 8
            for (int e = 0; e < DD; ++e)
                s += u.c.yv[e] * wc[(size_t)e * DD];
            u.c.y2[f] = s;
        }
        __syncthreads();

        // 5) h = gelu(y2 @ h1w + h1b)  -> LDS
        if (tid < HH) {
            float s = p.h1b[t * HH + tid];
            const float* wc = p.h1w + (size_t)t * DD * HH + tid;
#pragma unroll 8
            for (int f = 0; f < DD; ++f)
                s += u.c.y2[f] * wc[(size_t)f * HH];
            u.c.hv[tid] = 0.5f * s * (1.0f + erff(s * GELU_C));
        }
        __syncthreads();

        // 6) out = h @ h2w + h2b
        if (tid < OO) {
            float s = p.h2b[t * OO + tid];
#pragma unroll 8
            for (int j = 0; j < HH; ++j)
                s += u.c.hv[j] * p.h2w[((size_t)t * HH + j) * OO + tid];
            p.out[((size_t)t * BB + b) * OO + tid] = s;
        }
        __syncthreads();
    }
}

// ---------------------------------------------------------------------------
extern "C" void kernel_launch(void* const* d_in, const int* in_sizes, int n_in,
                              void* d_out, int out_size, void* d_ws, size_t ws_size,
                              hipStream_t stream) {
    Params P;
    P.x    = (const float*)d_in[0];
    P.mask = (const int*)d_in[1];   // True = masked
    P.tt   = (const float*)d_in[2];
    P.Wq   = (const float*)d_in[3];
    P.bq   = (const float*)d_in[4];
    P.Wk   = (const float*)d_in[5];
    // d_in[6] = bk: cancels in softmax
    P.Wv   = (const float*)d_in[7];
    P.bv   = (const float*)d_in[8];
    P.Wo   = (const float*)d_in[9];
    P.bo   = (const float*)d_in[10];
    P.h1w  = (const float*)d_in[11];
    P.h1b  = (const float*)d_in[12];
    P.h2w  = (const float*)d_in[13];
    P.h2b  = (const float*)d_in[14];
    P.out  = (float*)d_out;

    // barrier region: 1024 packed arrival dwords (4KB) + 256 release lines (16KB)
    P.arr = (unsigned*)d_ws;
    P.rel = P.arr + 1024;
    float* fws = (float*)((char*)d_ws + 32 * 1024);
    P.q     = fws;                              // 2304
    P.kq    = P.q + TT * DD;                    // 2304
    P.xap   = P.kq + TT * DD;                   // 1024*2304
    P.lp    = P.xap + (size_t)VC * TT * DD;     // 3072

    // Co-residency-safe grid from the runtime's own occupancy accounting.
    int grid = 512;                              // conservative fallback
    int dev = 0, cus = 0, perCU = 0;
    if (hipGetDevice(&dev) == hipSuccess &&
        hipDeviceGetAttribute(&cus, hipDeviceAttributeMultiprocessorCount, dev) == hipSuccess &&
        hipOccupancyMaxActiveBlocksPerMultiprocessor(&perCU, (const void*)fused, 256, 0) == hipSuccess &&
        cus > 0 && perCU > 0) {
        long g = (long)cus * (long)perCU;
        grid = (int)(g < 1024 ? g : 1024);
    }

    hipMemsetAsync(d_ws, 0, 32 * 1024, stream);  // zero arrival+release words
    Params Pl = P;
    hipLaunchKernelGGL(fused, dim3(grid), dim3(256), 0, stream, Pl);
}

// Round 11
// 167.564 us; speedup vs baseline: 2.0013x; 2.0013x over previous
//
#include <hip/hip_runtime.h>
#include <math.h>

// Problem constants
#define BB 32
#define PP 2048
#define DD 768
#define TT 3
#define OO 128
#define HH 192
#define VC2 2048           // main-phase tasks (32 rows each): 64 chunks/batch
#define ASTR 16            // padded slot stride (64B lines)
#define SCALE 0.03608439182435161f  // 1/sqrt(768)
#define GELU_C 0.70710678118654752f

struct Params {
    const float* x; const int* mask; const float* tt;
    const float* Wq; const float* bq; const float* Wk;
    const float* Wv; const float* bv; const float* Wo; const float* bo;
    const float* h1w; const float* h1b; const float* h2w; const float* h2b;
    float* out;
    unsigned* arr;     // 1024 packed arrival dwords
    unsigned* rel;     // 256 padded release lines (<=4 pollers each)
    unsigned* ctr;     // 8 padded task counters
    unsigned* qdone;   // 3 padded q-completion counters
    float* q; float* kq; float* xap; float* lp; float* xa;
    float* partV; float* partO; float* partH;
};

// L3-coherent (L2-bypassing) accessors for inter-phase intermediates.
__device__ inline float ld(const float* p) {
    return __hip_atomic_load(p, __ATOMIC_RELAXED, __HIP_MEMORY_SCOPE_AGENT);
}
__device__ inline void st(float* p, float v) {
    __hip_atomic_store(p, v, __ATOMIC_RELAXED, __HIP_MEMORY_SCOPE_AGENT);
}
__device__ inline unsigned ldu(const unsigned* p) {
    return __hip_atomic_load(p, __ATOMIC_RELAXED, __HIP_MEMORY_SCOPE_AGENT);
}

// ---------------------------------------------------------------------------
// Grid barrier v3 (round-8 verified) — zero cache-maintenance ops.
// ---------------------------------------------------------------------------
__device__ inline void gbar(unsigned* arr, unsigned* rel, int phase) {
    __syncthreads();   // drains vmcnt/lgkmcnt for every wave of this block
    const int grid = gridDim.x;
    const unsigned ph = (unsigned)phase;
    if (blockIdx.x == 0) {
        if (threadIdx.x == 0)
            __hip_atomic_store(&arr[0], ph, __ATOMIC_RELAXED,
                               __HIP_MEMORY_SCOPE_AGENT);
        for (unsigned it = 0; it < (1u << 22); ++it) {
            int ok = 1;
            for (int s = threadIdx.x; s < grid; s += 256)
                ok &= (ldu(&arr[s]) >= ph);
            if (__syncthreads_and(ok)) break;
            __builtin_amdgcn_s_sleep(1);
        }
        asm volatile("" ::: "memory");
        __hip_atomic_store(&rel[threadIdx.x * ASTR], ph, __ATOMIC_RELAXED,
                           __HIP_MEMORY_SCOPE_AGENT);
        __syncthreads();
    } else {
        if (threadIdx.x == 0) {
            __hip_atomic_store(&arr[blockIdx.x], ph, __ATOMIC_RELAXED,
                               __HIP_MEMORY_SCOPE_AGENT);
            unsigned* myrel = &rel[(blockIdx.x & 255) * ASTR];
            for (unsigned it = 0; it < (1u << 22); ++it) {
                if (ldu(myrel) >= ph) break;
                __builtin_amdgcn_s_sleep(1);
            }
            asm volatile("" ::: "memory");
        }
        __syncthreads();
    }
}

// ---------------------------------------------------------------------------
// One fused kernel, work-stealing phases / 6 grid barriers.
//  A: q(144)+kq(576) via q-done counters | P3 main(2048) | P4 comb(96) |
//  P5 V(288) | P6 O(288) | P7 H(72) | P8 tail(96)
// ---------------------------------------------------------------------------
__global__ __launch_bounds__(256, 4) void fused(Params p) {
    __shared__ union {
        struct { float red[4][TT * DD]; float redl[4][TT]; } m;    // 36912 B
        float qred[16][16];
        float ins[BB][96];
        float hl[HH];
    } u;
    __shared__ unsigned tsk;

    const int tid = threadIdx.x;

    // task-steal helper: block-uniform grab from counter c
#define GRAB(cidx, N, idvar)                                                  \
    __syncthreads();                                                          \
    if (tid == 0) tsk = __hip_atomic_fetch_add(&p.ctr[(cidx) * ASTR], 1u,     \
                        __ATOMIC_RELAXED, __HIP_MEMORY_SCOPE_AGENT);          \
    __syncthreads();                                                          \
    unsigned idvar = tsk;                                                     \
    if (idvar >= (N)) break;

    // ---- Phase A: q tasks (ids 0..143) then kq tasks (ids 144..719) -------
    for (;;) {
        GRAB(0, 720u, id)
        if (id < 144u) {
            int t = id / 48, ec = id % 48;
            int le = tid & 15, kg = tid >> 4;
            int e = ec * 16 + le;
            const float* w  = p.Wq + (size_t)t * DD * DD + e;
            const float* tr = p.tt + t * DD;
            float a = 0.f;
#pragma unroll 4
            for (int d = kg * 48; d < kg * 48 + 48; ++d)
                a += tr[d] * w[(size_t)d * DD];
            u.qred[kg][le] = a;
            __syncthreads();
            if (kg == 0) {
                float s = p.bq[t * DD + e];
#pragma unroll
                for (int i = 0; i < 16; ++i) s += u.qred[i][le];
                st(&p.q[t * DD + e], s);
            }
            // mark q-chunk done: stores (wave 0 only) must be at L3 first
            if (tid == 0) {
                asm volatile("s_waitcnt vmcnt(0)" ::: "memory");
                __hip_atomic_fetch_add(&p.qdone[t * ASTR], 1u,
                                       __ATOMIC_RELAXED, __HIP_MEMORY_SCOPE_AGENT);
            }
        } else {
            unsigned vb = id - 144u;
            int t = vb / 192;
            // wait until all 48 q-chunks of this t are published
            if (tid == 0) {
                for (unsigned it = 0; it < (1u << 22); ++it) {
                    if (ldu(&p.qdone[t * ASTR]) >= 48u) break;
                    __builtin_amdgcn_s_sleep(1);
                }
                asm volatile("" ::: "memory");
            }
            __syncthreads();
            int d = (vb % 192) * 4 + (tid >> 6);
            int L = tid & 63;
            const float4* wr = (const float4*)(p.Wk + (size_t)(t * DD + d) * DD);
            const float* qb = p.q + t * DD;
            float s = 0.f;
#pragma unroll
            for (int g = 0; g < 3; ++g) {
                float4 a = wr[g * 64 + L];
                int qi = g * 256 + 4 * L;
                s += a.x * ld(&qb[qi]) + a.y * ld(&qb[qi + 1])
                   + a.z * ld(&qb[qi + 2]) + a.w * ld(&qb[qi + 3]);
            }
#pragma unroll
            for (int off = 32; off; off >>= 1) s += __shfl_xor(s, off);
            if (L == 0) st(&p.kq[t * DD + d], s * SCALE);
        }
    }
    gbar(p.arr, p.rel, 1);

    // ---- Phase 3: MAIN stream over x (2048 stolen tasks, 32 rows each) ----
    {
        const int w = tid >> 6, L = tid & 63;
        float4 kqr[TT][3];
#pragma unroll
        for (int t = 0; t < TT; ++t)
#pragma unroll
            for (int g = 0; g < 3; ++g) {
                int base = t * DD + g * 256 + 4 * L;
                kqr[t][g].x = ld(&p.kq[base]);
                kqr[t][g].y = ld(&p.kq[base + 1]);
                kqr[t][g].z = ld(&p.kq[base + 2]);
                kqr[t][g].w = ld(&p.kq[base + 3]);
            }

        for (;;) {
            GRAB(1, (unsigned)VC2, id)
            int b = id >> 6, c = id & 63;

            float4 acc[TT][3] = {};
            float l[TT] = {0.f, 0.f, 0.f};
            const float* xb = p.x + (size_t)b * PP * DD;
            const int* mb = p.mask + b * PP;
            int p0 = c * 32 + w * 8;

            const int4* m4 = (const int4*)&mb[p0];
            int4 ma = m4[0], mb2 = m4[1];
            unsigned bits = 0;
            bits |= (ma.x  != 0) << 0; bits |= (ma.y  != 0) << 1;
            bits |= (ma.z  != 0) << 2; bits |= (ma.w  != 0) << 3;
            bits |= (mb2.x != 0) << 4; bits |= (mb2.y != 0) << 5;
            bits |= (mb2.z != 0) << 6; bits |= (mb2.w != 0) << 7;

#pragma unroll 4
            for (int r = 0; r < 8; ++r) {
                if (bits & (1u << r)) continue;    // masked rows contribute 0
                const float4* xr = (const float4*)(xb + (size_t)(p0 + r) * DD);
                float4 xv[3];
#pragma unroll
                for (int g = 0; g < 3; ++g) xv[g] = xr[g * 64 + L];
                float s[TT];
#pragma unroll
                for (int t = 0; t < TT; ++t) {
                    float a = 0.f;
#pragma unroll
                    for (int g = 0; g < 3; ++g)
                        a += xv[g].x * kqr[t][g].x + xv[g].y * kqr[t][g].y
                           + xv[g].z * kqr[t][g].z + xv[g].w * kqr[t][g].w;
                    s[t] = a;
                }
#pragma unroll
                for (int off = 32; off; off >>= 1) {
                    s[0] += __shfl_xor(s[0], off);
                    s[1] += __shfl_xor(s[1], off);
                    s[2] += __shfl_xor(s[2], off);
                }
#pragma unroll
                for (int t = 0; t < TT; ++t) {
                    float e = __expf(s[t]);        // scores tiny; no max needed
                    l[t] += e;
#pragma unroll
                    for (int g = 0; g < 3; ++g) {
                        acc[t][g].x += e * xv[g].x;
                        acc[t][g].y += e * xv[g].y;
                        acc[t][g].z += e * xv[g].z;
                        acc[t][g].w += e * xv[g].w;
                    }
                }
            }

            __syncthreads();
#pragma unroll
            for (int t = 0; t < TT; ++t)
#pragma unroll
                for (int g = 0; g < 3; ++g)
                    *(float4*)&u.m.red[w][t * DD + g * 256 + 4 * L] = acc[t][g];
            if (L == 0) {
#pragma unroll
                for (int t = 0; t < TT; ++t) u.m.redl[w][t] = l[t];
            }
            __syncthreads();

            float* outp = p.xap + (size_t)id * (TT * DD);
#pragma unroll
            for (int k = 0; k < 9; ++k) {
                int i = tid + k * 256;
                st(&outp[i], u.m.red[0][i] + u.m.red[1][i]
                           + u.m.red[2][i] + u.m.red[3][i]);
            }
            if (tid < TT)
                st(&p.lp[id * TT + tid], u.m.redl[0][tid] + u.m.redl[1][tid]
                                       + u.m.redl[2][tid] + u.m.redl[3][tid]);
        }
    }
    gbar(p.arr, p.rel, 2);

    // ---- Phase 4: combine chunk partials -> xa  (96 tasks) ----------------
    for (;;) {
        GRAB(2, (unsigned)(TT * BB), id)
        int t = id >> 5, b = id & 31;
        float lsum = 0.f;
#pragma unroll 8
        for (int c = 0; c < 64; ++c) lsum += ld(&p.lp[(b * 64 + c) * TT + t]);
        float inv = 1.0f / lsum;
#pragma unroll
        for (int k = 0; k < 3; ++k) {
            int d = tid + k * 256;
            float s = 0.f;
#pragma unroll 8
            for (int c = 0; c < 64; ++c)
                s += ld(&p.xap[(size_t)(b * 64 + c) * (TT * DD) + t * DD + d]);
            st(&p.xa[(t * BB + b) * DD + d], s * inv);
        }
    }
    gbar(p.arr, p.rel, 3);

    // ---- Phase 5: P1V — partV from xa @ Wv  (288 tasks) -------------------
    for (;;) {
        GRAB(3, (unsigned)(TT * 96), id)
        int t = id / 96, r = id % 96, kc = r / 12, ec = r % 12;
        for (int i = tid; i < BB * 96; i += 256) {
            int b = i / 96, kk = i % 96;
            u.ins[b][kk] = ld(&p.xa[((size_t)t * BB + b) * DD + kc * 96 + kk]);
        }
        __syncthreads();
        int le = tid & 63, bg = tid >> 6;
        int e = ec * 64 + le;
        const float* wp = p.Wv + (size_t)t * DD * DD + (size_t)(kc * 96) * DD + e;
        float acc[8] = {};
#pragma unroll 4
        for (int kk = 0; kk < 96; ++kk) {
            float wv = wp[(size_t)kk * DD];
#pragma unroll
            for (int j = 0; j < 8; ++j) acc[j] += u.ins[bg * 8 + j][kk] * wv;
        }
#pragma unroll
        for (int j = 0; j < 8; ++j)
            st(&p.partV[(((size_t)t * 8 + kc) * BB + (bg * 8 + j)) * DD + e], acc[j]);
    }
    gbar(p.arr, p.rel, 4);

    // ---- Phase 6: P1O — y = reduce(partV)+bv, times Wo  (288 tasks) -------
    for (;;) {
        GRAB(4, (unsigned)(TT * 96), id)
        int t = id / 96, r = id % 96, kc = r / 12, ec = r % 12;
        for (int i = tid; i < BB * 96; i += 256) {
            int b = i / 96, kk = i % 96;
            int k = kc * 96 + kk;
            float s = p.bv[t * DD + k];
#pragma unroll
            for (int c8 = 0; c8 < 8; ++c8)
                s += ld(&p.partV[(((size_t)t * 8 + c8) * BB + b) * DD + k]);
            u.ins[b][kk] = s;
        }
        __syncthreads();
        int le = tid & 63, bg = tid >> 6;
        int e = ec * 64 + le;
        const float* wp = p.Wo + (size_t)t * DD * DD + (size_t)(kc * 96) * DD + e;
        float acc[8] = {};
#pragma unroll 4
        for (int kk = 0; kk < 96; ++kk) {
            float wv = wp[(size_t)kk * DD];
#pragma unroll
            for (int j = 0; j < 8; ++j) acc[j] += u.ins[bg * 8 + j][kk] * wv;
        }
#pragma unroll
        for (int j = 0; j < 8; ++j)
            st(&p.partO[(((size_t)t * 8 + kc) * BB + (bg * 8 + j)) * DD + e], acc[j]);
    }
    gbar(p.arr, p.rel, 5);

    // ---- Phase 7: P1H — y2 = reduce(partO)+bo+tt, times h1w  (72 tasks) ---
    for (;;) {
        GRAB(5, (unsigned)(TT * 24), id)
        int t = id / 24, r = id % 24, kc = r / 3, ec = r % 3;
        for (int i = tid; i < BB * 96; i += 256) {
            int b = i / 96, kk = i % 96;
            int k = kc * 96 + kk;
            float s = p.bo[t * DD + k] + p.tt[t * DD + k];
#pragma unroll
            for (int c8 = 0; c8 < 8; ++c8)
                s += ld(&p.partO[(((size_t)t * 8 + c8) * BB + b) * DD + k]);
            u.ins[b][kk] = s;
        }
        __syncthreads();
        int le = tid & 63, bg = tid >> 6;
        int e = ec * 64 + le;  // 0..191
        const float* wp = p.h1w + (size_t)t * DD * HH + (size_t)(kc * 96) * HH + e;
        float acc[8] = {};
#pragma unroll 4
        for (int kk = 0; kk < 96; ++kk) {
            float wv = wp[(size_t)kk * HH];
#pragma unroll
            for (int j = 0; j < 8; ++j) acc[j] += u.ins[bg * 8 + j][kk] * wv;
        }
#pragma unroll
        for (int j = 0; j < 8; ++j)
            st(&p.partH[(((size_t)t * 8 + kc) * BB + (bg * 8 + j)) * HH + e], acc[j]);
    }
    gbar(p.arr, p.rel, 6);

    // ---- Phase 8: TAIL — h = gelu(reduce(partH)+h1b); out = h@h2w+h2b -----
    for (;;) {
        GRAB(6, (unsigned)(TT * BB), id)
        int t = id / BB, b = id % BB;
        if (tid < HH) {
            float s = p.h1b[t * HH + tid];
#pragma unroll
            for (int kc = 0; kc < 8; ++kc)
                s += ld(&p.partH[(((size_t)t * 8 + kc) * BB + b) * HH + tid]);
            u.hl[tid] = 0.5f * s * (1.0f + erff(s * GELU_C));
        }
        __syncthreads();
        if (tid < OO) {
            float s = p.h2b[t * OO + tid];
#pragma unroll 8
            for (int kh = 0; kh < HH; ++kh)
                s += u.hl[kh] * p.h2w[((size_t)t * HH + kh) * OO + tid];
            p.out[((size_t)t * BB + b) * OO + tid] = s;
        }
    }
#undef GRAB
}

// ---------------------------------------------------------------------------
extern "C" void kernel_launch(void* const* d_in, const int* in_sizes, int n_in,
                              void* d_out, int out_size, void* d_ws, size_t ws_size,
                              hipStream_t stream) {
    Params P;
    P.x    = (const float*)d_in[0];
    P.mask = (const int*)d_in[1];   // True = masked
    P.tt   = (const float*)d_in[2];
    P.Wq   = (const float*)d_in[3];
    P.bq   = (const float*)d_in[4];
    P.Wk   = (const float*)d_in[5];
    // d_in[6] = bk: cancels in softmax
    P.Wv   = (const float*)d_in[7];
    P.bv   = (const float*)d_in[8];
    P.Wo   = (const float*)d_in[9];
    P.bo   = (const float*)d_in[10];
    P.h1w  = (const float*)d_in[11];
    P.h1b  = (const float*)d_in[12];
    P.h2w  = (const float*)d_in[13];
    P.h2b  = (const float*)d_in[14];
    P.out  = (float*)d_out;

    // control region (zeroed each launch): arr 4KB | rel 16KB | ctr 512B | qdone
    P.arr   = (unsigned*)d_ws;
    P.rel   = P.arr + 1024;
    P.ctr   = P.rel + 256 * ASTR;
    P.qdone = P.ctr + 8 * ASTR;
    float* fws = (float*)((char*)d_ws + 32 * 1024);
    P.q     = fws;                              // 2304
    P.kq    = P.q + TT * DD;                    // 2304
    P.xap   = P.kq + TT * DD;                   // 2048*2304 (18.9 MB)
    P.lp    = P.xap + (size_t)VC2 * TT * DD;    // 6144
    P.xa    = P.lp + VC2 * TT;                  // 73728
    P.partV = P.xa + TT * BB * DD;              // 589824
    P.partO = P.partV + TT * 8 * BB * DD;       // 589824
    P.partH = P.partO + TT * 8 * BB * DD;       // 147456

    // Co-residency-safe grid from the runtime's own occupancy accounting.
    int grid = 512;                              // conservative fallback
    int dev = 0, cus = 0, perCU = 0;
    if (hipGetDevice(&dev) == hipSuccess &&
        hipDeviceGetAttribute(&cus, hipDeviceAttributeMultiprocessorCount, dev) == hipSuccess &&
        hipOccupancyMaxActiveBlocksPerMultiprocessor(&perCU, (const void*)fused, 256, 0) == hipSuccess &&
        cus > 0 && perCU > 0) {
        long g = (long)cus * (long)perCU;
        grid = (int)(g < 1024 ? g : 1024);
    }

    hipMemsetAsync(d_ws, 0, 32 * 1024, stream);  // zero arr/rel/ctr/qdone
    Params Pl = P;
    hipLaunchKernelGGL(fused, dim3(grid), dim3(256), 0, stream, Pl);
}